// Round 4
// baseline (161.709 us; speedup 1.0000x reference)
//
#include <hip/hip_runtime.h>
#include <hip/hip_bf16.h>
#include <math.h>

#define B_ROWS 16384
#define C_COLS 1000
#define C_PAD  1024
#define FDIM   1024
#define FBLKS  4096           // feature normalize blocks (4 rows each)
#define FP8_SCALE 256.0f      // pre-scale before e4m3 quant (avoids subnormals)
#define INV_SIM   (1.0f / (FP8_SCALE * FP8_SCALE))
#define GRID_GEMM 1024        // must be exactly co-resident: 4 blocks/CU x 256 CU

typedef __attribute__((ext_vector_type(8))) short bf16x8;
typedef __attribute__((ext_vector_type(4))) float f32x4;
typedef __attribute__((ext_vector_type(4))) int   i32x4;
typedef __attribute__((ext_vector_type(8))) int   i32x8;

// async global->LDS, 16B per lane; lds dst is wave-uniform base (HW puts lane i at base + i*16)
#define GLD_LDS(gp, lp) __builtin_amdgcn_global_load_lds( \
    (__attribute__((address_space(1))) void*)(gp),        \
    (__attribute__((address_space(3))) void*)(lp), 16, 0, 0)

static __device__ __forceinline__ unsigned int pack2bf(float a, float b) {
    __hip_bfloat16 ha = __float2bfloat16(a), hb = __float2bfloat16(b);
    unsigned short ua, ub;
    __builtin_memcpy(&ua, &ha, 2);
    __builtin_memcpy(&ub, &hb, 2);
    return (unsigned int)ua | ((unsigned int)ub << 16);
}
static __device__ __forceinline__ float unpackbf(unsigned int w, int hi) {
    unsigned short us = (unsigned short)(hi ? (w >> 16) : (w & 0xffff));
    __hip_bfloat16 h;
    __builtin_memcpy(&h, &us, 2);
    return __bfloat162float(h);
}

// ---------------- fused row L2-normalize fp32 -> fp8 e4m3 (x256), one wave per row ---------
__global__ __launch_bounds__(256) void normalize_all(
    const float* __restrict__ feat, const float* __restrict__ prot,
    unsigned char* __restrict__ fb, unsigned char* __restrict__ pb,
    float* __restrict__ rowsum, unsigned int* __restrict__ barrier_ctr)
{
    const int lane = threadIdx.x & 63;
    const int wave = threadIdx.x >> 6;

    // fold rowsum zeroing into the first 64 blocks (replaces the memset dispatch);
    // block 64 re-arms the spin-barrier counter for this graph iteration
    if (blockIdx.x < 64) rowsum[blockIdx.x * 256 + threadIdx.x] = 0.0f;
    if (blockIdx.x == 64 && threadIdx.x == 0) *barrier_ctr = 0u;

    const float* in;
    unsigned char* out;
    int row, nvalid;
    if (blockIdx.x < FBLKS) {
        row = blockIdx.x * 4 + wave;  in = feat; out = fb; nvalid = B_ROWS;
    } else {
        row = (blockIdx.x - FBLKS) * 4 + wave;  in = prot; out = pb; nvalid = C_COLS;
    }
    unsigned char* orow = out + (size_t)row * FDIM;

    if (row >= nvalid) {               // zero-pad prototype rows 1000..1023
        i32x4 z = {0, 0, 0, 0};
        ((i32x4*)orow)[lane] = z;      // 64 lanes x 16 B = 1024 B row
        return;
    }

    // lane owns 16 contiguous elements -> one 16 B fp8 store
    const float4* rp = (const float4*)(in + (size_t)row * FDIM);
    float4 v[4];
    float ss = 0.0f;
    #pragma unroll
    for (int c = 0; c < 4; ++c) {
        v[c] = rp[lane * 4 + c];
        ss += v[c].x * v[c].x + v[c].y * v[c].y + v[c].z * v[c].z + v[c].w * v[c].w;
    }
    #pragma unroll
    for (int off = 1; off < 64; off <<= 1) ss += __shfl_xor(ss, off, 64);
    const float inv = FP8_SCALE / sqrtf(fmaxf(ss, 1e-24f));

    i32x4 pk;
    #pragma unroll
    for (int c = 0; c < 4; ++c) {
        int w0 = __builtin_amdgcn_cvt_pk_fp8_f32(v[c].x * inv, v[c].y * inv, 0, false);
        w0     = __builtin_amdgcn_cvt_pk_fp8_f32(v[c].z * inv, v[c].w * inv, w0, true);
        pk[c] = w0;
    }
    ((i32x4*)orow)[lane] = pk;
}

// one 128x128x1024 MX-fp8 GEMM tile into ACC (acc stays fp32 sim*65536)
#define GEMM_TILE(BM_, BN_, ACC) do {                                                        \
    const unsigned char* Abase_ = A  + ((size_t)((BM_) * 128 + wave * 8 + srow8)) * FDIM + sg * 16; \
    const unsigned char* Bbase_ = Bp + ((size_t)((BN_) * 128 + wave * 8 + srow8)) * FDIM + sg * 16; \
    _Pragma("unroll 1")                                                                      \
    for (int k0_ = 0; k0_ < FDIM; k0_ += 128) {                                              \
        __syncthreads();                                                                     \
        _Pragma("unroll")                                                                    \
        for (int r_ = 0; r_ < 4; ++r_) {                                                     \
            GLD_LDS(Abase_ + (size_t)(r_ * 32) * FDIM + k0_, &As[(r_ * 32 + wave * 8) * 128]); \
            GLD_LDS(Bbase_ + (size_t)(r_ * 32) * FDIM + k0_, &Bs[(r_ * 32 + wave * 8) * 128]); \
        }                                                                                    \
        __syncthreads();                                                                     \
        i32x8 bfr_[4];                                                                       \
        _Pragma("unroll")                                                                    \
        for (int nt_ = 0; nt_ < 4; ++nt_) {                                                  \
            const i32x4 lo_ = *(const i32x4*)&Bs[fB + nt_ * 2048 + pg0];                     \
            const i32x4 hi_ = *(const i32x4*)&Bs[fB + nt_ * 2048 + pg1];                     \
            bfr_[nt_] = (i32x8){lo_.x, lo_.y, lo_.z, lo_.w, hi_.x, hi_.y, hi_.z, hi_.w};     \
        }                                                                                    \
        _Pragma("unroll")                                                                    \
        for (int mt_ = 0; mt_ < 4; ++mt_) {                                                  \
            const i32x4 lo_ = *(const i32x4*)&As[fA + mt_ * 2048 + pg0];                     \
            const i32x4 hi_ = *(const i32x4*)&As[fA + mt_ * 2048 + pg1];                     \
            const i32x8 a_ = (i32x8){lo_.x, lo_.y, lo_.z, lo_.w, hi_.x, hi_.y, hi_.z, hi_.w};\
            _Pragma("unroll")                                                                \
            for (int nt_ = 0; nt_ < 4; ++nt_)                                                \
                ACC[mt_][nt_] = __builtin_amdgcn_mfma_scale_f32_16x16x128_f8f6f4(            \
                    a_, bfr_[nt_], ACC[mt_][nt_], 0, 0, 0, 127, 0, 127);                     \
        }                                                                                    \
    }                                                                                        \
} while (0)

// ---------------- fused GEMM + distance + device spin-barrier + final write ----------------
// Same 1024-block / 1-tile / 4-blocks-per-CU structure as the proven gemm_dist (identical
// main-loop register pressure). Distances packed to bf16 regs (32 VGPRs) across the barrier.
// Grid barrier = arrive-and-spin counter (graph-capture safe, unlike coop launch).
// Co-residency gated host-side via occupancy query; fallback otherwise.
__global__ __launch_bounds__(256) void gemm_spin_out(
    const unsigned char* __restrict__ A,
    const unsigned char* __restrict__ Bp,
    float* __restrict__ rowsum,
    unsigned int* __restrict__ barrier_ctr,
    const float* __restrict__ scale,
    const float* __restrict__ temp,
    float* __restrict__ out)
{
    __shared__ unsigned char As[128 * 128];   // 16 KB
    __shared__ unsigned char Bs[128 * 128];   // 16 KB

    const int tid  = threadIdx.x;
    const int lane = tid & 63;
    const int wave = tid >> 6;

    // XCD swizzle: the 8 bn-blocks of one bm share id%8 (same XCD) for A-tile L2 reuse
    const int id  = blockIdx.x;             // 0..1023
    const int xcd = id & 7;
    const int seq = id >> 3;                // 0..127
    const int bn  = seq & 7;                // 0..7
    const int bm  = xcd * 16 + (seq >> 3);  // 0..127

    const int waveM = (wave >> 1) * 64;
    const int waveN = (wave & 1) * 64;

    const int srow8 = lane >> 3;
    const int sg    = (lane & 7) ^ srow8;
    const int q2   = (lane >> 4) * 2;
    const int bxor = lane & 7;
    const int fA = (waveM + (lane & 15)) * 128;
    const int fB = (waveN + (lane & 15)) * 128;
    const int pg0 = ((q2)     ^ bxor) * 16;
    const int pg1 = ((q2 + 1) ^ bxor) * 16;

    const int row0 = bm * 128 + waveM;
    const int col0 = bn * 128 + waveN;

    // phase 1: GEMM -> distances -> pack to bf16 regs + rowsum atomics
    unsigned int pk1[4][4][2];    // 32 VGPRs live across the barrier
    {
        f32x4 acc[4][4] = {};
        GEMM_TILE(bm, bn, acc);

        #pragma unroll
        for (int mt = 0; mt < 4; ++mt) {
            #pragma unroll
            for (int r = 0; r < 4; ++r) {
                float part = 0.0f;
                #pragma unroll
                for (int nt = 0; nt < 4; ++nt) {
                    const float sim = acc[mt][nt][r] * INV_SIM;
                    const float dv = sqrtf(fmaxf(1.0f - sim, 0.0f));
                    acc[mt][nt][r] = dv;
                    const int col = col0 + nt * 16 + (lane & 15);
                    if (col < C_COLS) part += dv;
                }
                part += __shfl_xor(part, 1, 64);
                part += __shfl_xor(part, 2, 64);
                part += __shfl_xor(part, 4, 64);
                part += __shfl_xor(part, 8, 64);
                if ((lane & 15) == 0)
                    atomicAdd(&rowsum[row0 + mt * 16 + (lane >> 4) * 4 + r], part);
            }
            #pragma unroll
            for (int nt = 0; nt < 4; ++nt) {
                pk1[mt][nt][0] = pack2bf(acc[mt][nt][0], acc[mt][nt][1]);
                pk1[mt][nt][1] = pack2bf(acc[mt][nt][2], acc[mt][nt][3]);
            }
        }
    }

    // grid-wide spin barrier (all blocks co-resident by construction)
    if (tid == 0) {
        __threadfence();                  // release: rowsum atomics visible device-wide
        atomicAdd(barrier_ctr, 1u);
        while (__hip_atomic_load(barrier_ctr, __ATOMIC_RELAXED,
                                 __HIP_MEMORY_SCOPE_AGENT) < (unsigned)GRID_GEMM) {
            __builtin_amdgcn_s_sleep(16);
        }
    }
    __syncthreads();
    __threadfence();                      // acquire side

    // phase 2: out = (-|ds|/T) * (d + rowsum/1000), unpacked from bf16 regs (fp32 store)
    const float aS = -fabsf(scale[0]) / temp[0];
    #pragma unroll
    for (int mt = 0; mt < 4; ++mt) {
        #pragma unroll
        for (int r = 0; r < 4; ++r) {
            const int row = row0 + mt * 16 + (lane >> 4) * 4 + r;
            const float m = __hip_atomic_load(&rowsum[row], __ATOMIC_RELAXED,
                                              __HIP_MEMORY_SCOPE_AGENT) * (1.0f / (float)C_COLS);
            #pragma unroll
            for (int nt = 0; nt < 4; ++nt) {
                const int col = col0 + nt * 16 + (lane & 15);
                if (col < C_COLS) {
                    const float dv = unpackbf(pk1[mt][nt][r >> 1], r & 1);
                    out[(size_t)row * C_COLS + col] = aS * (dv + m);
                }
            }
        }
    }
}

// ---------------- fallback path (proven baseline): GEMM -> D bf16 -> finalize --------------
__global__ __launch_bounds__(256) void gemm_dist(
    const unsigned char* __restrict__ A,
    const unsigned char* __restrict__ Bp,
    __hip_bfloat16* __restrict__ D,
    float* __restrict__ rowsum)
{
    __shared__ unsigned char As[128 * 128];
    __shared__ unsigned char Bs[128 * 128];

    const int tid  = threadIdx.x;
    const int lane = tid & 63;
    const int wave = tid >> 6;

    const int id  = blockIdx.x;
    const int xcd = id & 7;
    const int seq = id >> 3;
    const int bn  = seq & 7;
    const int bm  = xcd * 16 + (seq >> 3);

    const int waveM = (wave >> 1) * 64;
    const int waveN = (wave & 1) * 64;

    f32x4 acc[4][4] = {};

    const int srow8 = lane >> 3;
    const int sg    = (lane & 7) ^ srow8;
    const int q2   = (lane >> 4) * 2;
    const int bxor = lane & 7;
    const int fA = (waveM + (lane & 15)) * 128;
    const int fB = (waveN + (lane & 15)) * 128;
    const int pg0 = ((q2)     ^ bxor) * 16;
    const int pg1 = ((q2 + 1) ^ bxor) * 16;

    GEMM_TILE(bm, bn, acc);

    const int row0 = bm * 128 + waveM;
    const int col0 = bn * 128 + waveN;
    #pragma unroll
    for (int mt = 0; mt < 4; ++mt) {
        #pragma unroll
        for (int r = 0; r < 4; ++r) {
            const int row = row0 + mt * 16 + (lane >> 4) * 4 + r;
            float part = 0.0f;
            #pragma unroll
            for (int nt = 0; nt < 4; ++nt) {
                const int col = col0 + nt * 16 + (lane & 15);
                const float sim = acc[mt][nt][r] * INV_SIM;
                const float dv = sqrtf(fmaxf(1.0f - sim, 0.0f));
                if (col < C_COLS) {
                    D[(size_t)row * C_COLS + col] = __float2bfloat16(dv);
                    part += dv;
                }
            }
            part += __shfl_xor(part, 1, 64);
            part += __shfl_xor(part, 2, 64);
            part += __shfl_xor(part, 4, 64);
            part += __shfl_xor(part, 8, 64);
            if ((lane & 15) == 0) atomicAdd(&rowsum[row], part);
        }
    }
}

__global__ __launch_bounds__(256) void finalize(
    const __hip_bfloat16* __restrict__ D, const float* __restrict__ rowsum,
    const float* __restrict__ scale, const float* __restrict__ temp,
    float* __restrict__ out)
{
    const size_t i = (size_t)blockIdx.x * 256 + threadIdx.x;   // 8-element group
    const float a = -fabsf(scale[0]) / temp[0];
    const int row = (int)((i * 8) / C_COLS);                   // 1000 % 8 == 0, no straddle
    const float m = rowsum[row] * (1.0f / (float)C_COLS);

    const bf16x8 dv = *(const bf16x8*)(D + i * 8);
    const __hip_bfloat16* dp = (const __hip_bfloat16*)&dv;
    float4 o0, o1;
    o0.x = a * (__bfloat162float(dp[0]) + m);
    o0.y = a * (__bfloat162float(dp[1]) + m);
    o0.z = a * (__bfloat162float(dp[2]) + m);
    o0.w = a * (__bfloat162float(dp[3]) + m);
    o1.x = a * (__bfloat162float(dp[4]) + m);
    o1.y = a * (__bfloat162float(dp[5]) + m);
    o1.z = a * (__bfloat162float(dp[6]) + m);
    o1.w = a * (__bfloat162float(dp[7]) + m);
    ((float4*)out)[i * 2]     = o0;
    ((float4*)out)[i * 2 + 1] = o1;
}

extern "C" void kernel_launch(void* const* d_in, const int* in_sizes, int n_in,
                              void* d_out, int out_size, void* d_ws, size_t ws_size,
                              hipStream_t stream)
{
    const float* features = (const float*)d_in[0];   // [16384,1024]
    const float* protos   = (const float*)d_in[1];   // [1000,1024]
    const float* dscale   = (const float*)d_in[2];   // [1]
    const float* temp     = (const float*)d_in[3];   // [1]
    float* out = (float*)d_out;                      // [16384,1000]

    char* ws = (char*)d_ws;
    unsigned char* fb = (unsigned char*)ws;                       // 16,777,216 B
    unsigned char* pb = (unsigned char*)(ws + 16777216);          //  1,048,576 B
    __hip_bfloat16* D = (__hip_bfloat16*)(ws + 17825792);         // 32,768,000 B (fallback only)
    float* rowsum     = (float*)(ws + 50593792);                  //     65,536 B
    unsigned int* ctr = (unsigned int*)(ws + 50659328);           //          4 B

    normalize_all<<<FBLKS + C_PAD / 4, 256, 0, stream>>>(features, protos, fb, pb, rowsum, ctr);

    // decide fused vs fallback ONCE (host-side occupancy query only; capture-safe).
    // The spin barrier REQUIRES all 1024 blocks co-resident: 4 blocks/CU on 256 CUs.
    static int use_spin = -1;
    if (use_spin < 0) {
        int dev = 0;
        (void)hipGetDevice(&dev);
        int numCU = 0;
        (void)hipDeviceGetAttribute(&numCU, hipDeviceAttributeMultiprocessorCount, dev);
        int maxB = 0;
        hipError_t oe = hipOccupancyMaxActiveBlocksPerMultiprocessor(
            &maxB, reinterpret_cast<const void*>(gemm_spin_out), 256, 0);
        use_spin = (oe == hipSuccess && numCU > 0 &&
                    (long)maxB * numCU >= GRID_GEMM) ? 1 : 0;
    }

    if (use_spin) {
        gemm_spin_out<<<GRID_GEMM, 256, 0, stream>>>(fb, pb, rowsum, ctr, dscale, temp, out);
    } else {
        gemm_dist<<<1024, 256, 0, stream>>>(fb, pb, D, rowsum);
        finalize<<<(B_ROWS * C_COLS / 8) / 256, 256, 0, stream>>>(D, rowsum, dscale, temp, out);
    }
}

// Round 5
// 160.958 us; speedup vs baseline: 1.0047x; 1.0047x over previous
//
#include <hip/hip_runtime.h>
#include <hip/hip_bf16.h>
#include <math.h>

#define B_ROWS 16384
#define C_COLS 1000
#define C_PAD  1024
#define FDIM   1024
#define FBLKS  4096           // feature normalize blocks (4 rows each)
#define FP8_SCALE 256.0f      // pre-scale before e4m3 quant (avoids subnormals)
#define INV_SIM   (1.0f / (FP8_SCALE * FP8_SCALE))

typedef __attribute__((ext_vector_type(8))) short bf16x8;
typedef __attribute__((ext_vector_type(4))) float f32x4;
typedef __attribute__((ext_vector_type(4))) int   i32x4;
typedef __attribute__((ext_vector_type(8))) int   i32x8;

// async global->LDS, 16B per lane; lds dst is wave-uniform base (HW puts lane i at base + i*16)
#define GLD_LDS(gp, lp) __builtin_amdgcn_global_load_lds( \
    (__attribute__((address_space(1))) void*)(gp),        \
    (__attribute__((address_space(3))) void*)(lp), 16, 0, 0)

// ---------------- fused row L2-normalize fp32 -> fp8 e4m3 (x256), one wave per row ---------
__global__ __launch_bounds__(256) void normalize_all(
    const float* __restrict__ feat, const float* __restrict__ prot,
    unsigned char* __restrict__ fb, unsigned char* __restrict__ pb,
    float* __restrict__ rowsum)
{
    const int lane = threadIdx.x & 63;
    const int wave = threadIdx.x >> 6;

    // fold rowsum zeroing into the first 64 blocks (replaces the memset dispatch)
    if (blockIdx.x < 64) rowsum[blockIdx.x * 256 + threadIdx.x] = 0.0f;

    const float* in;
    unsigned char* out;
    int row, nvalid;
    if (blockIdx.x < FBLKS) {
        row = blockIdx.x * 4 + wave;  in = feat; out = fb; nvalid = B_ROWS;
    } else {
        row = (blockIdx.x - FBLKS) * 4 + wave;  in = prot; out = pb; nvalid = C_COLS;
    }
    unsigned char* orow = out + (size_t)row * FDIM;

    if (row >= nvalid) {               // zero-pad prototype rows 1000..1023
        i32x4 z = {0, 0, 0, 0};
        ((i32x4*)orow)[lane] = z;      // 64 lanes x 16 B = 1024 B row
        return;
    }

    // lane owns 16 contiguous elements -> one 16 B fp8 store
    const float4* rp = (const float4*)(in + (size_t)row * FDIM);
    float4 v[4];
    float ss = 0.0f;
    #pragma unroll
    for (int c = 0; c < 4; ++c) {
        v[c] = rp[lane * 4 + c];
        ss += v[c].x * v[c].x + v[c].y * v[c].y + v[c].z * v[c].z + v[c].w * v[c].w;
    }
    #pragma unroll
    for (int off = 1; off < 64; off <<= 1) ss += __shfl_xor(ss, off, 64);
    const float inv = FP8_SCALE / sqrtf(fmaxf(ss, 1e-24f));

    i32x4 pk;
    #pragma unroll
    for (int c = 0; c < 4; ++c) {
        int w0 = __builtin_amdgcn_cvt_pk_fp8_f32(v[c].x * inv, v[c].y * inv, 0, false);
        w0     = __builtin_amdgcn_cvt_pk_fp8_f32(v[c].z * inv, v[c].w * inv, w0, true);
        pk[c] = w0;
    }
    ((i32x4*)orow)[lane] = pk;
}

// ---------------- MX-fp8 GEMM 128x128, BK=128, double-buffered 2-phase pipeline ------------
// T3-minimum schedule: issue stage(t+1) into buf^1 BEFORE computing buf, then ONE
// __syncthreads per K-step. Its implicit vmcnt(0) drain lands after ~16 MFMA + 16 ds_read
// of compute have covered the L2->LDS latency (old loop drained immediately: 2 barriers,
// zero overlap -> MfmaUtil 15%). LDS 64KB -> 2 blocks/CU; within-block stage||compute
// overlap replaces the lost cross-block overlap (HK precedent: 1 block/CU, 70% peak).
// LDS tile [128 rows][128 B]; 16B granule g stored at phys slot (g ^ (row&7)) -> 2-way free.
__global__ __launch_bounds__(256) void gemm_dist(
    const unsigned char* __restrict__ A,
    const unsigned char* __restrict__ Bp,
    __hip_bfloat16* __restrict__ D,
    float* __restrict__ rowsum)
{
    __shared__ unsigned char As[2 * 128 * 128];   // 32 KB (double-buffered)
    __shared__ unsigned char Bs[2 * 128 * 128];   // 32 KB

    const int tid  = threadIdx.x;
    const int lane = tid & 63;
    const int wave = tid >> 6;

    // XCD swizzle: the 8 bn-blocks of one bm share id%8 (same XCD) for A-tile L2 reuse
    const int id  = blockIdx.x;             // 0..1023
    const int xcd = id & 7;
    const int seq = id >> 3;                // 0..127
    const int bn  = seq & 7;                // 0..7
    const int bm  = xcd * 16 + (seq >> 3);  // 0..127

    const int waveM = (wave >> 1) * 64;
    const int waveN = (wave & 1) * 64;

    f32x4 acc[4][4] = {};

    // staging: round r covers rows [r*32, r*32+32); wave w -> rows r*32+w*8 .. +8
    // lane i -> row +(i>>3), phys granule i&7, fetching logical granule (i&7)^(i>>3)
    const int srow8 = lane >> 3;
    const int sg    = (lane & 7) ^ srow8;
    const unsigned char* Abase = A  + ((size_t)(bm * 128 + wave * 8 + srow8)) * FDIM + sg * 16;
    const unsigned char* Bbase = Bp + ((size_t)(bn * 128 + wave * 8 + srow8)) * FDIM + sg * 16;

    // frag addressing: R = waveX + mt*16 + (lane&15); R&7 = lane&7.
    // logical granules for this lane: 2q, 2q+1 (q = lane>>4); phys = g ^ (lane&7)
    const int q2   = (lane >> 4) * 2;
    const int bxor = lane & 7;
    const int fA = (waveM + (lane & 15)) * 128;
    const int fB = (waveN + (lane & 15)) * 128;
    const int pg0 = ((q2)     ^ bxor) * 16;
    const int pg1 = ((q2 + 1) ^ bxor) * 16;

    const int ldsRow = wave * 8 * 128;      // this wave's staging base within a tile

    // prologue: stage K-step 0 into buffer 0; single drain
    #pragma unroll
    for (int r = 0; r < 4; ++r) {
        GLD_LDS(Abase + (size_t)(r * 32) * FDIM, &As[ldsRow + r * 32 * 128]);
        GLD_LDS(Bbase + (size_t)(r * 32) * FDIM, &Bs[ldsRow + r * 32 * 128]);
    }
    __syncthreads();

    #pragma unroll 1
    for (int t = 0; t < 8; ++t) {
        const int cur = (t & 1) << 14;      // byte offset of current buffer (0 / 16384)
        const int nxt = cur ^ 16384;

        // issue next K-step's stage FIRST (lands during compute; drained by the
        // implicit vmcnt(0) inside the end-of-iteration __syncthreads)
        if (t < 7) {
            const int k0n = (t + 1) * 128;
            #pragma unroll
            for (int r = 0; r < 4; ++r) {
                GLD_LDS(Abase + (size_t)(r * 32) * FDIM + k0n, &As[nxt + ldsRow + r * 32 * 128]);
                GLD_LDS(Bbase + (size_t)(r * 32) * FDIM + k0n, &Bs[nxt + ldsRow + r * 32 * 128]);
            }
        }

        // compute current buffer
        i32x8 b[4];
        #pragma unroll
        for (int nt = 0; nt < 4; ++nt) {
            const i32x4 lo = *(const i32x4*)&Bs[cur + fB + nt * 2048 + pg0];
            const i32x4 hi = *(const i32x4*)&Bs[cur + fB + nt * 2048 + pg1];
            b[nt] = (i32x8){lo.x, lo.y, lo.z, lo.w, hi.x, hi.y, hi.z, hi.w};
        }
        #pragma unroll
        for (int mt = 0; mt < 4; ++mt) {
            const i32x4 lo = *(const i32x4*)&As[cur + fA + mt * 2048 + pg0];
            const i32x4 hi = *(const i32x4*)&As[cur + fA + mt * 2048 + pg1];
            const i32x8 a = (i32x8){lo.x, lo.y, lo.z, lo.w, hi.x, hi.y, hi.z, hi.w};
            #pragma unroll
            for (int nt = 0; nt < 4; ++nt)
                acc[mt][nt] = __builtin_amdgcn_mfma_scale_f32_16x16x128_f8f6f4(
                    a, b[nt], acc[mt][nt], 0, 0, /*opsel_a*/0, /*scale_a*/127, /*opsel_b*/0, /*scale_b*/127);
        }

        // one barrier per K-step: waits own ds_reads (already consumed by MFMA) and
        // drains the in-flight stage -> buffer swap is safe
        __syncthreads();
    }

    // epilogue: sim = acc/65536; d = sqrt(max(1-sim,0)); C/D: col=lane&15, row=(lane>>4)*4+reg
    const int row0 = bm * 128 + waveM;
    const int col0 = bn * 128 + waveN;
    #pragma unroll
    for (int mt = 0; mt < 4; ++mt) {
        #pragma unroll
        for (int r = 0; r < 4; ++r) {
            const int row = row0 + mt * 16 + (lane >> 4) * 4 + r;
            float part = 0.0f;
            #pragma unroll
            for (int nt = 0; nt < 4; ++nt) {
                const int col = col0 + nt * 16 + (lane & 15);
                const float sim = acc[mt][nt][r] * INV_SIM;
                const float dv = sqrtf(fmaxf(1.0f - sim, 0.0f));
                if (col < C_COLS) {
                    D[(size_t)row * C_COLS + col] = __float2bfloat16(dv);
                    part += dv;
                }
            }
            part += __shfl_xor(part, 1, 64);
            part += __shfl_xor(part, 2, 64);
            part += __shfl_xor(part, 4, 64);
            part += __shfl_xor(part, 8, 64);
            if ((lane & 15) == 0) atomicAdd(&rowsum[row], part);
        }
    }
}

// ---------------- finalize: out = (-|ds|/T) * (d + rowsum/1000) ----------------
__global__ __launch_bounds__(256) void finalize(
    const __hip_bfloat16* __restrict__ D, const float* __restrict__ rowsum,
    const float* __restrict__ scale, const float* __restrict__ temp,
    float* __restrict__ out)
{
    const size_t i = (size_t)blockIdx.x * 256 + threadIdx.x;   // 8-element group
    const float a = -fabsf(scale[0]) / temp[0];
    const int row = (int)((i * 8) / C_COLS);                   // 1000 % 8 == 0, no straddle
    const float m = rowsum[row] * (1.0f / (float)C_COLS);

    const bf16x8 dv = *(const bf16x8*)(D + i * 8);
    const __hip_bfloat16* dp = (const __hip_bfloat16*)&dv;
    float4 o0, o1;
    o0.x = a * (__bfloat162float(dp[0]) + m);
    o0.y = a * (__bfloat162float(dp[1]) + m);
    o0.z = a * (__bfloat162float(dp[2]) + m);
    o0.w = a * (__bfloat162float(dp[3]) + m);
    o1.x = a * (__bfloat162float(dp[4]) + m);
    o1.y = a * (__bfloat162float(dp[5]) + m);
    o1.z = a * (__bfloat162float(dp[6]) + m);
    o1.w = a * (__bfloat162float(dp[7]) + m);
    ((float4*)out)[i * 2]     = o0;
    ((float4*)out)[i * 2 + 1] = o1;
}

extern "C" void kernel_launch(void* const* d_in, const int* in_sizes, int n_in,
                              void* d_out, int out_size, void* d_ws, size_t ws_size,
                              hipStream_t stream)
{
    const float* features = (const float*)d_in[0];   // [16384,1024]
    const float* protos   = (const float*)d_in[1];   // [1000,1024]
    const float* dscale   = (const float*)d_in[2];   // [1]
    const float* temp     = (const float*)d_in[3];   // [1]
    float* out = (float*)d_out;                      // [16384,1000]

    char* ws = (char*)d_ws;
    unsigned char* fb = (unsigned char*)ws;                       // 16,777,216 B
    unsigned char* pb = (unsigned char*)(ws + 16777216);          //  1,048,576 B
    __hip_bfloat16* D = (__hip_bfloat16*)(ws + 17825792);         // 32,768,000 B
    float* rowsum     = (float*)(ws + 50593792);                  //     65,536 B

    normalize_all<<<FBLKS + C_PAD / 4, 256, 0, stream>>>(features, protos, fb, pb, rowsum);

    gemm_dist<<<1024, 256, 0, stream>>>(fb, pb, D, rowsum);

    finalize<<<(B_ROWS * C_COLS / 8) / 256, 256, 0, stream>>>(D, rowsum, dscale, temp, out);
}

// Round 6
// 159.164 us; speedup vs baseline: 1.0160x; 1.0113x over previous
//
#include <hip/hip_runtime.h>
#include <hip/hip_bf16.h>
#include <math.h>

#define B_ROWS 16384
#define C_COLS 1000
#define C_PAD  1024
#define FDIM   1024
#define FBLKS  4096           // feature normalize blocks (4 rows each)
#define FP8_SCALE 256.0f      // pre-scale before e4m3 quant (avoids subnormals)
#define INV_SIM   (1.0f / (FP8_SCALE * FP8_SCALE))

typedef __attribute__((ext_vector_type(8))) short bf16x8;
typedef __attribute__((ext_vector_type(4))) float f32x4;
typedef __attribute__((ext_vector_type(4))) int   i32x4;
typedef __attribute__((ext_vector_type(8))) int   i32x8;

// async global->LDS, 16B per lane; lds dst is wave-uniform base (HW puts lane i at base + i*16)
#define GLD_LDS(gp, lp) __builtin_amdgcn_global_load_lds( \
    (__attribute__((address_space(1))) void*)(gp),        \
    (__attribute__((address_space(3))) void*)(lp), 16, 0, 0)

// ---------------- fused row L2-normalize fp32 -> fp8 e4m3 (x256), one wave per row ---------
__global__ __launch_bounds__(256) void normalize_all(
    const float* __restrict__ feat, const float* __restrict__ prot,
    unsigned char* __restrict__ fb, unsigned char* __restrict__ pb,
    float* __restrict__ rowsum)
{
    const int lane = threadIdx.x & 63;
    const int wave = threadIdx.x >> 6;

    // fold rowsum zeroing into the first 64 blocks (replaces the memset dispatch)
    if (blockIdx.x < 64) rowsum[blockIdx.x * 256 + threadIdx.x] = 0.0f;

    const float* in;
    unsigned char* out;
    int row, nvalid;
    if (blockIdx.x < FBLKS) {
        row = blockIdx.x * 4 + wave;  in = feat; out = fb; nvalid = B_ROWS;
    } else {
        row = (blockIdx.x - FBLKS) * 4 + wave;  in = prot; out = pb; nvalid = C_COLS;
    }
    unsigned char* orow = out + (size_t)row * FDIM;

    if (row >= nvalid) {               // zero-pad prototype rows 1000..1023
        i32x4 z = {0, 0, 0, 0};
        ((i32x4*)orow)[lane] = z;      // 64 lanes x 16 B = 1024 B row
        return;
    }

    // lane owns 16 contiguous elements -> one 16 B fp8 store
    const float4* rp = (const float4*)(in + (size_t)row * FDIM);
    float4 v[4];
    float ss = 0.0f;
    #pragma unroll
    for (int c = 0; c < 4; ++c) {
        v[c] = rp[lane * 4 + c];
        ss += v[c].x * v[c].x + v[c].y * v[c].y + v[c].z * v[c].z + v[c].w * v[c].w;
    }
    #pragma unroll
    for (int off = 1; off < 64; off <<= 1) ss += __shfl_xor(ss, off, 64);
    const float inv = FP8_SCALE / sqrtf(fmaxf(ss, 1e-24f));

    i32x4 pk;
    #pragma unroll
    for (int c = 0; c < 4; ++c) {
        int w0 = __builtin_amdgcn_cvt_pk_fp8_f32(v[c].x * inv, v[c].y * inv, 0, false);
        w0     = __builtin_amdgcn_cvt_pk_fp8_f32(v[c].z * inv, v[c].w * inv, w0, true);
        pk[c] = w0;
    }
    ((i32x4*)orow)[lane] = pk;
}

// ---------------- MX-fp8 GEMM 128x128, BK=128, counted-vmcnt depth-2 pipeline (T3+T4) -----
// The r5 __syncthreads dbuf was exactly neutral (m99/m100 replication): the barrier's
// implicit vmcnt(0) drains the prefetch every K-step. This version keeps loads IN FLIGHT
// across raw s_barriers with counted s_waitcnt vmcnt(8): batch t+2 is issued after the
// all-waves-done-reading barrier of iter t, and only waited (vmcnt(8) = 8 newest still
// outstanding) at iter t+2's start -- a full iteration (~800cy) of MFMA covers the L2
// latency. setprio(1) wraps the MFMA cluster (T5; pays once phases exist).
// LDS tile [128 rows][128 B]; 16B granule g at phys slot (g ^ (row&7)) -> 2-way free.
__global__ __launch_bounds__(256) void gemm_dist(
    const unsigned char* __restrict__ A,
    const unsigned char* __restrict__ Bp,
    __hip_bfloat16* __restrict__ D,
    float* __restrict__ rowsum)
{
    __shared__ unsigned char As[2 * 128 * 128];   // 32 KB (double-buffered)
    __shared__ unsigned char Bs[2 * 128 * 128];   // 32 KB

    const int tid  = threadIdx.x;
    const int lane = tid & 63;
    const int wave = tid >> 6;

    // XCD swizzle: the 8 bn-blocks of one bm share id%8 (same XCD) for A-tile L2 reuse
    const int id  = blockIdx.x;             // 0..1023
    const int xcd = id & 7;
    const int seq = id >> 3;                // 0..127
    const int bn  = seq & 7;                // 0..7
    const int bm  = xcd * 16 + (seq >> 3);  // 0..127

    const int waveM = (wave >> 1) * 64;
    const int waveN = (wave & 1) * 64;

    f32x4 acc[4][4] = {};

    // staging: round r covers rows [r*32, r*32+32); wave w -> rows r*32+w*8 .. +8
    // lane i -> row +(i>>3), phys granule i&7, fetching logical granule (i&7)^(i>>3)
    const int srow8 = lane >> 3;
    const int sg    = (lane & 7) ^ srow8;
    const unsigned char* Abase = A  + ((size_t)(bm * 128 + wave * 8 + srow8)) * FDIM + sg * 16;
    const unsigned char* Bbase = Bp + ((size_t)(bn * 128 + wave * 8 + srow8)) * FDIM + sg * 16;

    // frag addressing: R = waveX + mt*16 + (lane&15); R&7 = lane&7.
    // logical granules for this lane: 2q, 2q+1 (q = lane>>4); phys = g ^ (lane&7)
    const int q2   = (lane >> 4) * 2;
    const int bxor = lane & 7;
    const int fA = (waveM + (lane & 15)) * 128;
    const int fB = (waveN + (lane & 15)) * 128;
    const int pg0 = ((q2)     ^ bxor) * 16;
    const int pg1 = ((q2 + 1) ^ bxor) * 16;

    const int ldsRow = wave * 8 * 128;      // this wave's staging base within a tile

    // prologue: batch0 -> buf0, batch1 -> buf1. sched_barrier keeps issue order so the
    // vmcnt retirement order equals batch order (vmcnt(8) <=> batch0 retired).
    #pragma unroll
    for (int r = 0; r < 4; ++r) {
        GLD_LDS(Abase + (size_t)(r * 32) * FDIM, &As[ldsRow + r * 32 * 128]);
        GLD_LDS(Bbase + (size_t)(r * 32) * FDIM, &Bs[ldsRow + r * 32 * 128]);
    }
    __builtin_amdgcn_sched_barrier(0);
    #pragma unroll
    for (int r = 0; r < 4; ++r) {
        GLD_LDS(Abase + (size_t)(r * 32) * FDIM + 128, &As[16384 + ldsRow + r * 32 * 128]);
        GLD_LDS(Bbase + (size_t)(r * 32) * FDIM + 128, &Bs[16384 + ldsRow + r * 32 * 128]);
    }
    __builtin_amdgcn_sched_barrier(0);

    #pragma unroll 1
    for (int t = 0; t < 7; ++t) {
        // own batch-t retired (8 newest = batch t+1 [+ t+2] still in flight), then
        // barrier => ALL waves' batch-t slices landed in buf[t&1]
        asm volatile("s_waitcnt vmcnt(8)" ::: "memory");
        __builtin_amdgcn_s_barrier();
        __builtin_amdgcn_sched_barrier(0);

        const int cur = (t & 1) << 14;      // byte offset of current buffer (0 / 16384)

        // frag reads (16 x ds_read_b128) into registers
        i32x8 a4[4], b4[4];
        #pragma unroll
        for (int nt = 0; nt < 4; ++nt) {
            const i32x4 lo = *(const i32x4*)&Bs[cur + fB + nt * 2048 + pg0];
            const i32x4 hi = *(const i32x4*)&Bs[cur + fB + nt * 2048 + pg1];
            b4[nt] = (i32x8){lo.x, lo.y, lo.z, lo.w, hi.x, hi.y, hi.z, hi.w};
        }
        #pragma unroll
        for (int mt = 0; mt < 4; ++mt) {
            const i32x4 lo = *(const i32x4*)&As[cur + fA + mt * 2048 + pg0];
            const i32x4 hi = *(const i32x4*)&As[cur + fA + mt * 2048 + pg1];
            a4[mt] = (i32x8){lo.x, lo.y, lo.z, lo.w, hi.x, hi.y, hi.z, hi.w};
        }

        // MFMA cluster (compiler inserts fine-grained lgkm waits for the frag loads)
        __builtin_amdgcn_s_setprio(1);
        #pragma unroll
        for (int mt = 0; mt < 4; ++mt)
            #pragma unroll
            for (int nt = 0; nt < 4; ++nt)
                acc[mt][nt] = __builtin_amdgcn_mfma_scale_f32_16x16x128_f8f6f4(
                    a4[mt], b4[nt], acc[mt][nt], 0, 0, 0, 127, 0, 127);
        __builtin_amdgcn_s_setprio(0);

        if (t < 6) {
            // all waves done READING buf[cur] (lgkm drained; MFMAs consumed the regs),
            // then overwrite buf[cur] with batch t+2. Loads stay in flight across the
            // next iteration's barrier (counted vmcnt -- the T4 point).
            asm volatile("s_waitcnt lgkmcnt(0)" ::: "memory");
            __builtin_amdgcn_s_barrier();
            __builtin_amdgcn_sched_barrier(0);
            const int k0n = (t + 2) * 128;
            #pragma unroll
            for (int r = 0; r < 4; ++r) {
                GLD_LDS(Abase + (size_t)(r * 32) * FDIM + k0n, &As[cur + ldsRow + r * 32 * 128]);
                GLD_LDS(Bbase + (size_t)(r * 32) * FDIM + k0n, &Bs[cur + ldsRow + r * 32 * 128]);
            }
            __builtin_amdgcn_sched_barrier(0);
        }
    }

    // peeled last K-step (t=7): buf1, full drain (nothing left to prefetch)
    asm volatile("s_waitcnt vmcnt(0)" ::: "memory");
    __builtin_amdgcn_s_barrier();
    __builtin_amdgcn_sched_barrier(0);
    {
        const int cur = 16384;
        i32x8 a4[4], b4[4];
        #pragma unroll
        for (int nt = 0; nt < 4; ++nt) {
            const i32x4 lo = *(const i32x4*)&Bs[cur + fB + nt * 2048 + pg0];
            const i32x4 hi = *(const i32x4*)&Bs[cur + fB + nt * 2048 + pg1];
            b4[nt] = (i32x8){lo.x, lo.y, lo.z, lo.w, hi.x, hi.y, hi.z, hi.w};
        }
        #pragma unroll
        for (int mt = 0; mt < 4; ++mt) {
            const i32x4 lo = *(const i32x4*)&As[cur + fA + mt * 2048 + pg0];
            const i32x4 hi = *(const i32x4*)&As[cur + fA + mt * 2048 + pg1];
            a4[mt] = (i32x8){lo.x, lo.y, lo.z, lo.w, hi.x, hi.y, hi.z, hi.w};
        }
        __builtin_amdgcn_s_setprio(1);
        #pragma unroll
        for (int mt = 0; mt < 4; ++mt)
            #pragma unroll
            for (int nt = 0; nt < 4; ++nt)
                acc[mt][nt] = __builtin_amdgcn_mfma_scale_f32_16x16x128_f8f6f4(
                    a4[mt], b4[nt], acc[mt][nt], 0, 0, 0, 127, 0, 127);
        __builtin_amdgcn_s_setprio(0);
    }

    // epilogue: sim = acc/65536; d = sqrt(max(1-sim,0)); C/D: col=lane&15, row=(lane>>4)*4+reg
    const int row0 = bm * 128 + waveM;
    const int col0 = bn * 128 + waveN;
    #pragma unroll
    for (int mt = 0; mt < 4; ++mt) {
        #pragma unroll
        for (int r = 0; r < 4; ++r) {
            const int row = row0 + mt * 16 + (lane >> 4) * 4 + r;
            float part = 0.0f;
            #pragma unroll
            for (int nt = 0; nt < 4; ++nt) {
                const int col = col0 + nt * 16 + (lane & 15);
                const float sim = acc[mt][nt][r] * INV_SIM;
                const float dv = sqrtf(fmaxf(1.0f - sim, 0.0f));
                if (col < C_COLS) {
                    D[(size_t)row * C_COLS + col] = __float2bfloat16(dv);
                    part += dv;
                }
            }
            part += __shfl_xor(part, 1, 64);
            part += __shfl_xor(part, 2, 64);
            part += __shfl_xor(part, 4, 64);
            part += __shfl_xor(part, 8, 64);
            if ((lane & 15) == 0) atomicAdd(&rowsum[row], part);
        }
    }
}

// ---------------- finalize: out = (-|ds|/T) * (d + rowsum/1000) ----------------
__global__ __launch_bounds__(256) void finalize(
    const __hip_bfloat16* __restrict__ D, const float* __restrict__ rowsum,
    const float* __restrict__ scale, const float* __restrict__ temp,
    float* __restrict__ out)
{
    const size_t i = (size_t)blockIdx.x * 256 + threadIdx.x;   // 8-element group
    const float a = -fabsf(scale[0]) / temp[0];
    const int row = (int)((i * 8) / C_COLS);                   // 1000 % 8 == 0, no straddle
    const float m = rowsum[row] * (1.0f / (float)C_COLS);

    const bf16x8 dv = *(const bf16x8*)(D + i * 8);
    const __hip_bfloat16* dp = (const __hip_bfloat16*)&dv;
    float4 o0, o1;
    o0.x = a * (__bfloat162float(dp[0]) + m);
    o0.y = a * (__bfloat162float(dp[1]) + m);
    o0.z = a * (__bfloat162float(dp[2]) + m);
    o0.w = a * (__bfloat162float(dp[3]) + m);
    o1.x = a * (__bfloat162float(dp[4]) + m);
    o1.y = a * (__bfloat162float(dp[5]) + m);
    o1.z = a * (__bfloat162float(dp[6]) + m);
    o1.w = a * (__bfloat162float(dp[7]) + m);
    ((float4*)out)[i * 2]     = o0;
    ((float4*)out)[i * 2 + 1] = o1;
}

extern "C" void kernel_launch(void* const* d_in, const int* in_sizes, int n_in,
                              void* d_out, int out_size, void* d_ws, size_t ws_size,
                              hipStream_t stream)
{
    const float* features = (const float*)d_in[0];   // [16384,1024]
    const float* protos   = (const float*)d_in[1];   // [1000,1024]
    const float* dscale   = (const float*)d_in[2];   // [1]
    const float* temp     = (const float*)d_in[3];   // [1]
    float* out = (float*)d_out;                      // [16384,1000]

    char* ws = (char*)d_ws;
    unsigned char* fb = (unsigned char*)ws;                       // 16,777,216 B
    unsigned char* pb = (unsigned char*)(ws + 16777216);          //  1,048,576 B
    __hip_bfloat16* D = (__hip_bfloat16*)(ws + 17825792);         // 32,768,000 B
    float* rowsum     = (float*)(ws + 50593792);                  //     65,536 B

    normalize_all<<<FBLKS + C_PAD / 4, 256, 0, stream>>>(features, protos, fb, pb, rowsum);

    gemm_dist<<<1024, 256, 0, stream>>>(fb, pb, D, rowsum);

    finalize<<<(B_ROWS * C_COLS / 8) / 256, 256, 0, stream>>>(D, rowsum, dscale, temp, out);
}